// Round 4
// baseline (231.875 us; speedup 1.0000x reference)
//
#include <hip/hip_runtime.h>
#include <hip/hip_bf16.h>

#define B_    32
#define C_    128
#define H_    56
#define W_    56
#define N_    3136
#define HK_   15
#define NK_   225
#define D_    64

typedef __attribute__((ext_vector_type(8))) short bf16x8;
typedef __attribute__((ext_vector_type(4))) float f32x4;

__device__ __forceinline__ float b2f(unsigned short u) {
    union { float f; unsigned int i; } x;
    x.i = ((unsigned int)u) << 16;
    return x.f;
}
__device__ __forceinline__ unsigned short f2b(float f) {
    __hip_bfloat16 h = __float2bfloat16(f);
    return *(unsigned short*)&h;
}

// ---------------- Kernel 1: fused sr (dw4x4 s4 + BN + ReLU + scale + BN) + local 3x3 + residual ----
__global__ __launch_bounds__(256) void srlocal_kernel(
        const float* __restrict__ x,
        const float* __restrict__ sr1_w,
        const float* __restrict__ sr1_g,
        const float* __restrict__ sr1_b,
        const float* __restrict__ sr1_m,
        const float* __restrict__ sr1_v,
        const float* __restrict__ sr2_w,
        const float* __restrict__ sr2_g,
        const float* __restrict__ sr2_b,
        const float* __restrict__ sr2_m,
        const float* __restrict__ sr2_v,
        const float* __restrict__ local_w,
        const float* __restrict__ local_b,
        float* __restrict__ kv2) {
    int bc = blockIdx.x;
    int c  = bc & (C_ - 1);
    int tid = threadIdx.x;
    __shared__ float xim[H_ * W_];       // 12.25 KB
    __shared__ float kvt[HK_][HK_ + 1];

    const float* xp = x + (size_t)bc * (H_ * W_);
    for (int idx = tid; idx < (H_ * W_) / 4; idx += 256)
        ((float4*)xim)[idx] = ((const float4*)xp)[idx];
    __syncthreads();

    int p = tid;
    int oy = p / HK_, ox = p % HK_;
    if (p < NK_) {
        float s = 0.f;
#pragma unroll
        for (int ky = 0; ky < 4; ++ky) {
            int iy = oy * 4 - 2 + ky;
            if (iy < 0 || iy >= H_) continue;
#pragma unroll
            for (int kx = 0; kx < 4; ++kx) {
                int ix = ox * 4 - 2 + kx;
                if (ix < 0 || ix >= W_) continue;
                s += xim[iy * W_ + ix] * sr1_w[c * 16 + ky * 4 + kx];
            }
        }
        float inv1 = sr1_g[c] * rsqrtf(sr1_v[c] + 1e-5f);
        s = (s - sr1_m[c]) * inv1 + sr1_b[c];
        s = fmaxf(s, 0.f);
        s *= sr2_w[c];
        float inv2 = sr2_g[c] * rsqrtf(sr2_v[c] + 1e-5f);
        s = (s - sr2_m[c]) * inv2 + sr2_b[c];
        kvt[oy][ox] = s;
    }
    __syncthreads();
    if (p < NK_) {
        float v = kvt[oy][ox] + local_b[c];
#pragma unroll
        for (int dy = -1; dy <= 1; ++dy) {
            int yy = oy + dy;
            if (yy < 0 || yy >= HK_) continue;
#pragma unroll
            for (int dx = -1; dx <= 1; ++dx) {
                int xx = ox + dx;
                if (xx < 0 || xx >= HK_) continue;
                v += kvt[yy][xx] * local_w[c * 9 + (dy + 1) * 3 + (dx + 1)];
            }
        }
        kv2[(size_t)bc * NK_ + p] = v;
    }
}

// ---------------- Kernel 2: kv proj -> KW (=k.q_w), bias_s (=q_b.k), V ----------------
// kw:     [bh][240][128] bf16  (rows >=225 zero)
// bias_s: [bh][240] f32        (entries >=225 = -1e30)
// vbuf:   [bh][64][256] bf16   (cols >=225 zero)
__global__ __launch_bounds__(256) void kvw_kernel(
        const float* __restrict__ kv2,
        const float* __restrict__ q_w,
        const float* __restrict__ q_b,
        const float* __restrict__ kv_w,
        const float* __restrict__ kv_b,
        unsigned short* __restrict__ kw,
        float* __restrict__ bias_s,
        unsigned short* __restrict__ vbuf) {
    int b = blockIdx.x, h = blockIdx.y, mc = blockIdx.z;
    int bh = b * 2 + h;
    int tid = threadIdx.x;
    int m0 = mc * 60;                       // this block: global m in [m0, m0+60)

    __shared__ unsigned short kv2s[128][62];   // [c][mm] bf16
    __shared__ unsigned short wk[64][130];
    __shared__ unsigned short wv[64][130];
    __shared__ unsigned short wq[64][130];
    __shared__ unsigned short kls[60][66];     // k'[mm][e] bf16 (0.125-scaled)
    __shared__ float qbs[64];

    for (int idx = tid; idx < 128 * 60; idx += 256) {
        int c = idx / 60, mm = idx % 60;
        int mg = m0 + mm;
        float v = (mg < NK_) ? kv2[((size_t)b * 128 + c) * NK_ + mg] : 0.f;
        kv2s[c][mm] = f2b(v);
    }
    for (int idx = tid; idx < 64 * 128; idx += 256) {
        int e = idx >> 7, c = idx & 127;
        wk[e][c] = f2b(kv_w[(size_t)(h * 64 + e) * 128 + c]);
        wv[e][c] = f2b(kv_w[(size_t)(128 + h * 64 + e) * 128 + c]);
        wq[e][c] = f2b(q_w[(size_t)(h * 64 + e) * 128 + c]);
    }
    if (tid < 64) qbs[tid] = q_b[h * 64 + tid];
    __syncthreads();

    // phase A: k'[mm][e] (scaled, incl bias) and v[e][mm]
    {
        int e = tid >> 2, mg4 = tid & 3;
        float acck[15], accv[15];
        float kb = kv_b[h * 64 + e];
        float vb = kv_b[128 + h * 64 + e];
#pragma unroll
        for (int i = 0; i < 15; ++i) { acck[i] = kb; accv[i] = vb; }
#pragma unroll 4
        for (int c = 0; c < 128; ++c) {
            float wkv = b2f(wk[e][c]);
            float wvv = b2f(wv[e][c]);
#pragma unroll
            for (int i = 0; i < 15; ++i) {
                float xv = b2f(kv2s[c][mg4 * 15 + i]);
                acck[i] += xv * wkv;
                accv[i] += xv * wvv;
            }
        }
#pragma unroll
        for (int i = 0; i < 15; ++i) {
            int mm = mg4 * 15 + i, mg = m0 + mm;
            kls[mm][e] = f2b(acck[i] * 0.125f);
            vbuf[((size_t)bh * 64 + e) * 256 + mg] = (mg < NK_) ? f2b(accv[i]) : (unsigned short)0;
        }
        if (mc == 3) {
            for (int idx = tid; idx < 64 * 16; idx += 256) {
                int e2 = idx >> 4, mm = idx & 15;
                vbuf[((size_t)bh * 64 + e2) * 256 + 240 + mm] = 0;
            }
        }
    }
    __syncthreads();

    // phase B: kw[mg][c] = sum_e k'[mm][e] * wq[e][c]
    {
        int c = tid & 127, mrow = tid >> 7;   // 30 m rows per thread
        float acc[30];
#pragma unroll
        for (int i = 0; i < 30; ++i) acc[i] = 0.f;
#pragma unroll 4
        for (int e = 0; e < 64; ++e) {
            float wvq = b2f(wq[e][c]);
#pragma unroll
            for (int i = 0; i < 30; ++i)
                acc[i] += b2f(kls[mrow * 30 + i][e]) * wvq;
        }
#pragma unroll
        for (int i = 0; i < 30; ++i) {
            int mm = mrow * 30 + i, mg = m0 + mm;
            kw[((size_t)bh * 240 + mg) * 128 + c] = (mg < NK_) ? f2b(acc[i]) : (unsigned short)0;
        }
    }
    // bias_s
    if (tid < 60) {
        int mm = tid, mg = m0 + mm;
        float s = 0.f;
#pragma unroll 8
        for (int e = 0; e < 64; ++e) s += qbs[e] * b2f(kls[mm][e]);
        bias_s[(size_t)bh * 240 + mg] = (mg < NK_) ? s : -1e30f;
    }
}

// ---------------- Kernel 3: fused attention (S = X^T.KW^T + bias, softmax, O^T = V^T.P^T) ----
#define XTB(j, c) ((j) * 256 + (((c) * 2) ^ (((j) & 7) << 4)))
#define PSB(j, m) ((j) * 512 + (((m) * 2) ^ (((j) & 7) << 4)))

__global__ __launch_bounds__(256, 4) void attn_kernel(
        const float* __restrict__ x,
        const unsigned short* __restrict__ kw,
        const float* __restrict__ bias_s,
        const unsigned short* __restrict__ vbuf,
        float* __restrict__ out) {
    int jt = blockIdx.x;        // 0..48
    int h  = blockIdx.y;        // 0..1
    int bb = blockIdx.z;        // 0..31
    int n0 = jt * 64;
    int bh = bb * 2 + h;
    int tid = threadIdx.x;
    int lo = tid & 15;
    int hi = (tid >> 4) & 3;
    int jw = (tid >> 6) * 16;

    __shared__ union {
        unsigned short xt[64 * 128];   // 16 KB, phase 1-2
        unsigned short ps[64 * 256];   // 32 KB, phase 3-4 (per-wave rows only)
    } R;
    char* xtB = (char*)R.xt;
    char* psB = (char*)R.ps;

    // preload bias (L2 broadcast)
    float bs[15];
    const float* bsp = bias_s + (size_t)bh * 240;
#pragma unroll
    for (int mt = 0; mt < 15; ++mt) bs[mt] = bsp[mt * 16 + lo];

    // P1: stage x^T tile (coalesced dword loads, reg transpose)
#pragma unroll
    for (int it = 0; it < 8; ++it) {
        int j  = tid & 63;
        int c0 = (tid >> 6) * 4 + it * 16;
        const float* xp = x + ((size_t)bb * 128 + c0) * N_ + n0 + j;
        ushort4 u;
        u.x = f2b(xp[0]);
        u.y = f2b(xp[(size_t)N_]);
        u.z = f2b(xp[2 * (size_t)N_]);
        u.w = f2b(xp[3 * (size_t)N_]);
        *(ushort4*)(xtB + XTB(j, c0)) = u;
    }
    __syncthreads();

    bf16x8 aq[4];
#pragma unroll
    for (int ks = 0; ks < 4; ++ks)
        aq[ks] = *(const bf16x8*)(xtB + XTB(jw + lo, ks * 32 + hi * 8));
    __syncthreads();            // xt region free after this point

    // P2: S[j][m] = sum_c xt[j][c] * kw[m][c]  (B-fragments from L2)
    const unsigned short* kwp = kw + (size_t)bh * 240 * 128;
    f32x4 s[15];
#pragma unroll
    for (int mt = 0; mt < 15; ++mt) {
        f32x4 acc = {0.f, 0.f, 0.f, 0.f};
#pragma unroll
        for (int ks = 0; ks < 4; ++ks) {
            bf16x8 bk = *(const bf16x8*)(kwp + (size_t)(mt * 16 + lo) * 128 + ks * 32 + hi * 8);
            acc = __builtin_amdgcn_mfma_f32_16x16x32_bf16(aq[ks], bk, acc, 0, 0, 0);
        }
        s[mt] = acc;
    }
#pragma unroll
    for (int mt = 0; mt < 15; ++mt) {
#pragma unroll
        for (int r = 0; r < 4; ++r) s[mt][r] += bs[mt];   // bias; -1e30 masks m>=225
    }

    // softmax over m (col index = lo lanes)
    float mx[4];
#pragma unroll
    for (int r = 0; r < 4; ++r) {
        float m0v = s[0][r];
#pragma unroll
        for (int mt = 1; mt < 15; ++mt) m0v = fmaxf(m0v, s[mt][r]);
        mx[r] = m0v;
    }
#pragma unroll
    for (int d = 1; d < 16; d <<= 1) {
#pragma unroll
        for (int r = 0; r < 4; ++r) mx[r] = fmaxf(mx[r], __shfl_xor(mx[r], d));
    }
    float sm[4] = {0.f, 0.f, 0.f, 0.f};
#pragma unroll
    for (int mt = 0; mt < 15; ++mt) {
#pragma unroll
        for (int r = 0; r < 4; ++r) {
            float pe = __expf(s[mt][r] - mx[r]);
            s[mt][r] = pe;
            sm[r] += pe;
        }
    }
#pragma unroll
    for (int d = 1; d < 16; d <<= 1) {
#pragma unroll
        for (int r = 0; r < 4; ++r) sm[r] += __shfl_xor(sm[r], d);
    }
    float rinv[4];
#pragma unroll
    for (int r = 0; r < 4; ++r) rinv[r] = 1.f / sm[r];

    // write normalized P (own wave's rows only -> no barrier needed)
#pragma unroll
    for (int mt = 0; mt < 15; ++mt) {
#pragma unroll
        for (int r = 0; r < 4; ++r)
            *(unsigned short*)(psB + PSB(jw + hi * 4 + r, mt * 16 + lo)) =
                f2b(s[mt][r] * rinv[r]);
    }
#pragma unroll
    for (int r = 0; r < 4; ++r)
        *(unsigned short*)(psB + PSB(jw + hi * 4 + r, 240 + lo)) = 0;

    // P3: O^T[e][j] = sum_m V^T[e][m] * P[j][m]  (A from L2 vbuf, B from own ps rows)
    bf16x8 bp[8];
#pragma unroll
    for (int ks = 0; ks < 8; ++ks)
        bp[ks] = *(const bf16x8*)(psB + PSB(jw + lo, ks * 32 + hi * 8));
    const unsigned short* vp0 = vbuf + (size_t)bh * 64 * 256;
#pragma unroll
    for (int et = 0; et < 4; ++et) {
        f32x4 acc = {0.f, 0.f, 0.f, 0.f};
#pragma unroll
        for (int ks = 0; ks < 8; ++ks) {
            bf16x8 av = *(const bf16x8*)(vp0 + (size_t)(et * 16 + lo) * 256 + ks * 32 + hi * 8);
            acc = __builtin_amdgcn_mfma_f32_16x16x32_bf16(av, bp[ks], acc, 0, 0, 0);
        }
        int e = et * 16 + hi * 4;
#pragma unroll
        for (int r = 0; r < 4; ++r)
            out[((size_t)bb * 128 + h * 64 + e + r) * N_ + n0 + jw + lo] = acc[r];
    }
}

extern "C" void kernel_launch(void* const* d_in, const int* in_sizes, int n_in,
                              void* d_out, int out_size, void* d_ws, size_t ws_size,
                              hipStream_t stream) {
    const float* x       = (const float*)d_in[0];
    const float* q_w     = (const float*)d_in[1];
    const float* q_b     = (const float*)d_in[2];
    const float* kv_w    = (const float*)d_in[3];
    const float* kv_b    = (const float*)d_in[4];
    const float* sr1_w   = (const float*)d_in[5];
    const float* sr1_g   = (const float*)d_in[6];
    const float* sr1_b   = (const float*)d_in[7];
    const float* sr1_m   = (const float*)d_in[8];
    const float* sr1_v   = (const float*)d_in[9];
    const float* sr2_w   = (const float*)d_in[10];
    const float* sr2_g   = (const float*)d_in[11];
    const float* sr2_b   = (const float*)d_in[12];
    const float* sr2_m   = (const float*)d_in[13];
    const float* sr2_v   = (const float*)d_in[14];
    const float* local_w = (const float*)d_in[15];
    const float* local_b = (const float*)d_in[16];

    // workspace layout
    float* kv2 = (float*)d_ws;                                        // 32*128*225 f32
    unsigned short* kw = (unsigned short*)(kv2 + (size_t)B_ * C_ * NK_); // 64*240*128 bf16
    float* bias_s = (float*)(kw + (size_t)64 * 240 * 128);            // 64*240 f32
    unsigned short* vbuf = (unsigned short*)(bias_s + (size_t)64 * 240); // 64*64*256 bf16

    srlocal_kernel<<<B_ * C_, 256, 0, stream>>>(
        x, sr1_w, sr1_g, sr1_b, sr1_m, sr1_v,
        sr2_w, sr2_g, sr2_b, sr2_m, sr2_v, local_w, local_b, kv2);
    kvw_kernel<<<dim3(B_, 2, 4), 256, 0, stream>>>(
        kv2, q_w, q_b, kv_w, kv_b, kw, bias_s, vbuf);
    attn_kernel<<<dim3(49, 2, B_), 256, 0, stream>>>(
        x, kw, bias_s, vbuf, (float*)d_out);
}

// Round 5
// 145.832 us; speedup vs baseline: 1.5900x; 1.5900x over previous
//
#include <hip/hip_runtime.h>
#include <hip/hip_bf16.h>

#define B_    32
#define C_    128
#define H_    56
#define W_    56
#define N_    3136
#define HK_   15
#define NK_   225
#define D_    64

typedef __attribute__((ext_vector_type(8))) short bf16x8;
typedef __attribute__((ext_vector_type(4))) float f32x4;

__device__ __forceinline__ float b2f(unsigned short u) {
    union { float f; unsigned int i; } x;
    x.i = ((unsigned int)u) << 16;
    return x.f;
}
__device__ __forceinline__ unsigned short f2b(float f) {
    __hip_bfloat16 h = __float2bfloat16(f);
    return *(unsigned short*)&h;
}

// async global -> LDS, 16B per lane. LDS dest must be wave-uniform base (HW adds lane*16).
__device__ __forceinline__ void gll16(const char* g, char* l) {
    __builtin_amdgcn_global_load_lds(
        (const __attribute__((address_space(1))) unsigned int*)g,
        (__attribute__((address_space(3))) unsigned int*)l,
        16, 0, 0);
}

// ---------------- Kernel 1: fused sr (dw4x4 s4 + BN + ReLU + scale + BN) + local 3x3 + residual ----
__global__ __launch_bounds__(256) void srlocal_kernel(
        const float* __restrict__ x,
        const float* __restrict__ sr1_w,
        const float* __restrict__ sr1_g,
        const float* __restrict__ sr1_b,
        const float* __restrict__ sr1_m,
        const float* __restrict__ sr1_v,
        const float* __restrict__ sr2_w,
        const float* __restrict__ sr2_g,
        const float* __restrict__ sr2_b,
        const float* __restrict__ sr2_m,
        const float* __restrict__ sr2_v,
        const float* __restrict__ local_w,
        const float* __restrict__ local_b,
        float* __restrict__ kv2) {
    int bc = blockIdx.x;
    int c  = bc & (C_ - 1);
    int tid = threadIdx.x;
    __shared__ float xim[H_ * W_];
    __shared__ float kvt[HK_][HK_ + 1];

    const float* xp = x + (size_t)bc * (H_ * W_);
    for (int idx = tid; idx < (H_ * W_) / 4; idx += 256)
        ((float4*)xim)[idx] = ((const float4*)xp)[idx];
    __syncthreads();

    int p = tid;
    int oy = p / HK_, ox = p % HK_;
    if (p < NK_) {
        float s = 0.f;
#pragma unroll
        for (int ky = 0; ky < 4; ++ky) {
            int iy = oy * 4 - 2 + ky;
            if (iy < 0 || iy >= H_) continue;
#pragma unroll
            for (int kx = 0; kx < 4; ++kx) {
                int ix = ox * 4 - 2 + kx;
                if (ix < 0 || ix >= W_) continue;
                s += xim[iy * W_ + ix] * sr1_w[c * 16 + ky * 4 + kx];
            }
        }
        float inv1 = sr1_g[c] * rsqrtf(sr1_v[c] + 1e-5f);
        s = (s - sr1_m[c]) * inv1 + sr1_b[c];
        s = fmaxf(s, 0.f);
        s *= sr2_w[c];
        float inv2 = sr2_g[c] * rsqrtf(sr2_v[c] + 1e-5f);
        s = (s - sr2_m[c]) * inv2 + sr2_b[c];
        kvt[oy][ox] = s;
    }
    __syncthreads();
    if (p < NK_) {
        float v = kvt[oy][ox] + local_b[c];
#pragma unroll
        for (int dy = -1; dy <= 1; ++dy) {
            int yy = oy + dy;
            if (yy < 0 || yy >= HK_) continue;
#pragma unroll
            for (int dx = -1; dx <= 1; ++dx) {
                int xx = ox + dx;
                if (xx < 0 || xx >= HK_) continue;
                v += kvt[yy][xx] * local_w[c * 9 + (dy + 1) * 3 + (dx + 1)];
            }
        }
        kv2[(size_t)bc * NK_ + p] = v;
    }
}

// ---------------- Kernel 2: kv proj -> KW (=k.q_w, swizzled), bias_s, V (swizzled) ----------------
// kw:     [bh][240] rows of 256B, byte col = (c*2) ^ ((m&7)<<4); rows >=225 zero
// bias_s: [bh][240] f32, entries >=225 = -1e30
// vbuf:   [bh][64] rows of 512B, byte col = (m*2) ^ ((e&7)<<4); m >=225 zero
__global__ __launch_bounds__(256) void kvw_kernel(
        const float* __restrict__ kv2,
        const float* __restrict__ q_w,
        const float* __restrict__ q_b,
        const float* __restrict__ kv_w,
        const float* __restrict__ kv_b,
        unsigned short* __restrict__ kw,
        float* __restrict__ bias_s,
        unsigned short* __restrict__ vbuf) {
    int b = blockIdx.x, h = blockIdx.y, mc = blockIdx.z;
    int bh = b * 2 + h;
    int tid = threadIdx.x;
    int m0 = mc * 60;

    char* kwB = (char*)kw + (size_t)bh * 240 * 256;
    char* vB  = (char*)vbuf + (size_t)bh * 64 * 512;

    __shared__ unsigned short kv2s[128][62];
    __shared__ unsigned short wk[64][130];
    __shared__ unsigned short wv[64][130];
    __shared__ unsigned short wq[64][130];
    __shared__ unsigned short kls[60][66];
    __shared__ float qbs[64];

    for (int idx = tid; idx < 128 * 60; idx += 256) {
        int c = idx / 60, mm = idx % 60;
        int mg = m0 + mm;
        float v = (mg < NK_) ? kv2[((size_t)b * 128 + c) * NK_ + mg] : 0.f;
        kv2s[c][mm] = f2b(v);
    }
    for (int idx = tid; idx < 64 * 128; idx += 256) {
        int e = idx >> 7, c = idx & 127;
        wk[e][c] = f2b(kv_w[(size_t)(h * 64 + e) * 128 + c]);
        wv[e][c] = f2b(kv_w[(size_t)(128 + h * 64 + e) * 128 + c]);
        wq[e][c] = f2b(q_w[(size_t)(h * 64 + e) * 128 + c]);
    }
    if (tid < 64) qbs[tid] = q_b[h * 64 + tid];
    __syncthreads();

    // phase A: k'[mm][e] (0.125-scaled) and v[e][m] (swizzled store)
    {
        int e = tid >> 2, mg4 = tid & 3;
        float acck[15], accv[15];
        float kb = kv_b[h * 64 + e];
        float vb = kv_b[128 + h * 64 + e];
#pragma unroll
        for (int i = 0; i < 15; ++i) { acck[i] = kb; accv[i] = vb; }
#pragma unroll 4
        for (int c = 0; c < 128; ++c) {
            float wkv = b2f(wk[e][c]);
            float wvv = b2f(wv[e][c]);
#pragma unroll
            for (int i = 0; i < 15; ++i) {
                float xv = b2f(kv2s[c][mg4 * 15 + i]);
                acck[i] += xv * wkv;
                accv[i] += xv * wvv;
            }
        }
#pragma unroll
        for (int i = 0; i < 15; ++i) {
            int mm = mg4 * 15 + i, mg = m0 + mm;
            kls[mm][e] = f2b(acck[i] * 0.125f);
            unsigned short val = (mg < NK_) ? f2b(accv[i]) : (unsigned short)0;
            *(unsigned short*)(vB + (size_t)e * 512 + (((mg * 2) ^ ((e & 7) << 4)))) = val;
        }
        if (mc == 3) {
            for (int idx = tid; idx < 64 * 16; idx += 256) {
                int e2 = idx >> 4, mm = idx & 15;
                int mcol = 240 + mm;
                *(unsigned short*)(vB + (size_t)e2 * 512 + (((mcol * 2) ^ ((e2 & 7) << 4)))) = 0;
            }
        }
    }
    __syncthreads();

    // phase B: kw[mg][c] = sum_e k'[mm][e] * wq[e][c]   (swizzled store)
    {
        int c = tid & 127, mrow = tid >> 7;
        float acc[30];
#pragma unroll
        for (int i = 0; i < 30; ++i) acc[i] = 0.f;
#pragma unroll 4
        for (int e = 0; e < 64; ++e) {
            float wvq = b2f(wq[e][c]);
#pragma unroll
            for (int i = 0; i < 30; ++i)
                acc[i] += b2f(kls[mrow * 30 + i][e]) * wvq;
        }
#pragma unroll
        for (int i = 0; i < 30; ++i) {
            int mm = mrow * 30 + i, mg = m0 + mm;
            unsigned short val = (mg < NK_) ? f2b(acc[i]) : (unsigned short)0;
            *(unsigned short*)(kwB + (size_t)mg * 256 + (((c * 2) ^ ((mg & 7) << 4)))) = val;
        }
    }
    if (tid < 60) {
        int mm = tid, mg = m0 + mm;
        float s = 0.f;
#pragma unroll 8
        for (int e = 0; e < 64; ++e) s += qbs[e] * b2f(kls[mm][e]);
        bias_s[(size_t)bh * 240 + mg] = (mg < NK_) ? s : -1e30f;
    }
}

// ---------------- Kernel 3: fused attention, LDS-fed MFMA ----------------
#define XTB(j, c) ((j) * 256 + (((c) * 2) ^ (((j) & 7) << 4)))
#define PSB(j, m) ((j) * 512 + (((m) * 2) ^ (((j) & 7) << 4)))
#define KWB(rl, cb) ((rl) * 256 + ((cb) ^ (((rl) & 7) << 4)))
#define CVB(e, cb)  ((e) * 512 + ((cb) ^ (((e) & 7) << 4)))

__global__ __launch_bounds__(256, 2) void attn_kernel(
        const float* __restrict__ x,
        const unsigned short* __restrict__ kw,
        const float* __restrict__ bias_s,
        const unsigned short* __restrict__ vbuf,
        float* __restrict__ out) {
    int jt = blockIdx.x;        // 0..48
    int h  = blockIdx.y;        // 0..1
    int bb = blockIdx.z;        // 0..31
    int n0 = jt * 64;
    int bh = bb * 2 + h;
    int tid = threadIdx.x;
    int lo  = tid & 15;
    int hi  = (tid >> 4) & 3;
    int wid = tid >> 6;
    int jw  = wid * 16;

    __shared__ char A[32768];    // xt (16KB) then ps (32KB)
    __shared__ char Bt[12288];   // kw tile: 48 rows x 256B
    __shared__ char Cv[32768];   // v: 64 rows x 512B

    const char* kwG = (const char*)kw + (size_t)bh * 240 * 256;
    const char* vG  = (const char*)vbuf + (size_t)bh * 64 * 512;

    // bias preload (independent, L2)
    float bs[15];
    const float* bsp = bias_s + (size_t)bh * 240;
#pragma unroll
    for (int mt = 0; mt < 15; ++mt) bs[mt] = bsp[mt * 16 + lo];

    // issue async staging: kw tile0 (12KB) + full V (32KB)
    {
        char* dstB = Bt + wid * 1024;
        const char* srcB = kwG + tid * 16;
#pragma unroll
        for (int i = 0; i < 3; ++i) gll16(srcB + i * 4096, dstB + i * 4096);
        char* dstC = Cv + wid * 1024;
        const char* srcC = vG + tid * 16;
#pragma unroll
        for (int i = 0; i < 8; ++i) gll16(srcC + i * 4096, dstC + i * 4096);
    }

    // stage x^T tile (reg transpose, f32 -> bf16)
#pragma unroll
    for (int it = 0; it < 8; ++it) {
        int j  = tid & 63;
        int c0 = (tid >> 6) * 4 + it * 16;
        const float* xp = x + ((size_t)bb * 128 + c0) * N_ + n0 + j;
        ushort4 u;
        u.x = f2b(xp[0]);
        u.y = f2b(xp[(size_t)N_]);
        u.z = f2b(xp[2 * (size_t)N_]);
        u.w = f2b(xp[3 * (size_t)N_]);
        *(ushort4*)(A + XTB(j, c0)) = u;
    }
    __syncthreads();   // drains gll (vmcnt) + xt writes (lgkm)

    // A-fragments (this wave's 16 j rows)
    bf16x8 aq[4];
#pragma unroll
    for (int ks = 0; ks < 4; ++ks)
        aq[ks] = *(const bf16x8*)(A + XTB(jw + lo, ks * 32 + hi * 8));

    // S phase: 5 kw-tiles of 48 m-rows, single-buffered (cross-block overlap hides staging)
    f32x4 s[15];
#pragma unroll
    for (int t = 0; t < 5; ++t) {
#pragma unroll
        for (int ml = 0; ml < 3; ++ml) {
            f32x4 acc = {0.f, 0.f, 0.f, 0.f};
#pragma unroll
            for (int ks = 0; ks < 4; ++ks) {
                bf16x8 bk = *(const bf16x8*)(Bt + KWB(ml * 16 + lo, ks * 64 + hi * 16));
                acc = __builtin_amdgcn_mfma_f32_16x16x32_bf16(aq[ks], bk, acc, 0, 0, 0);
            }
            s[t * 3 + ml] = acc;
        }
        if (t < 4) {
            __syncthreads();   // all waves done reading Bt
            const char* srcB = kwG + (t + 1) * 12288 + tid * 16;
            char* dstB = Bt + wid * 1024;
#pragma unroll
            for (int i = 0; i < 3; ++i) gll16(srcB + i * 4096, dstB + i * 4096);
            __syncthreads();   // drains gll before next reads
        }
    }

    // bias (+ -1e30 mask for m>=225)
#pragma unroll
    for (int mt = 0; mt < 15; ++mt) {
#pragma unroll
        for (int r = 0; r < 4; ++r) s[mt][r] += bs[mt];
    }

    // softmax over m
    float mx[4];
#pragma unroll
    for (int r = 0; r < 4; ++r) {
        float m0v = s[0][r];
#pragma unroll
        for (int mt = 1; mt < 15; ++mt) m0v = fmaxf(m0v, s[mt][r]);
        mx[r] = m0v;
    }
#pragma unroll
    for (int d = 1; d < 16; d <<= 1) {
#pragma unroll
        for (int r = 0; r < 4; ++r) mx[r] = fmaxf(mx[r], __shfl_xor(mx[r], d));
    }
    float sm[4] = {0.f, 0.f, 0.f, 0.f};
#pragma unroll
    for (int mt = 0; mt < 15; ++mt) {
#pragma unroll
        for (int r = 0; r < 4; ++r) {
            float pe = __expf(s[mt][r] - mx[r]);
            s[mt][r] = pe;
            sm[r] += pe;
        }
    }
#pragma unroll
    for (int d = 1; d < 16; d <<= 1) {
#pragma unroll
        for (int r = 0; r < 4; ++r) sm[r] += __shfl_xor(sm[r], d);
    }
    float rinv[4];
#pragma unroll
    for (int r = 0; r < 4; ++r) rinv[r] = 1.f / sm[r];

    // write normalized P into A (own wave's rows only; 8 barriers since aq reads -> safe)
#pragma unroll
    for (int mt = 0; mt < 15; ++mt) {
#pragma unroll
        for (int r = 0; r < 4; ++r)
            *(unsigned short*)(A + PSB(jw + hi * 4 + r, mt * 16 + lo)) =
                f2b(s[mt][r] * rinv[r]);
    }
#pragma unroll
    for (int r = 0; r < 4; ++r)
        *(unsigned short*)(A + PSB(jw + hi * 4 + r, 240 + lo)) = 0;

    // PV: O^T[e][j] = sum_m V^T[e][m] * P[j][m]; A-frags from Cv LDS, B-frags from own ps rows
    bf16x8 bp[8];
#pragma unroll
    for (int ks = 0; ks < 8; ++ks)
        bp[ks] = *(const bf16x8*)(A + PSB(jw + lo, ks * 32 + hi * 8));
#pragma unroll
    for (int et = 0; et < 4; ++et) {
        f32x4 acc = {0.f, 0.f, 0.f, 0.f};
#pragma unroll
        for (int ks = 0; ks < 8; ++ks) {
            bf16x8 av = *(const bf16x8*)(Cv + CVB(et * 16 + lo, ks * 64 + hi * 16));
            acc = __builtin_amdgcn_mfma_f32_16x16x32_bf16(av, bp[ks], acc, 0, 0, 0);
        }
        int e = et * 16 + hi * 4;
#pragma unroll
        for (int r = 0; r < 4; ++r)
            out[((size_t)bb * 128 + h * 64 + e + r) * N_ + n0 + jw + lo] = acc[r];
    }
}

extern "C" void kernel_launch(void* const* d_in, const int* in_sizes, int n_in,
                              void* d_out, int out_size, void* d_ws, size_t ws_size,
                              hipStream_t stream) {
    const float* x       = (const float*)d_in[0];
    const float* q_w     = (const float*)d_in[1];
    const float* q_b     = (const float*)d_in[2];
    const float* kv_w    = (const float*)d_in[3];
    const float* kv_b    = (const float*)d_in[4];
    const float* sr1_w   = (const float*)d_in[5];
    const float* sr1_g   = (const float*)d_in[6];
    const float* sr1_b   = (const float*)d_in[7];
    const float* sr1_m   = (const float*)d_in[8];
    const float* sr1_v   = (const float*)d_in[9];
    const float* sr2_w   = (const float*)d_in[10];
    const float* sr2_g   = (const float*)d_in[11];
    const float* sr2_b   = (const float*)d_in[12];
    const float* sr2_m   = (const float*)d_in[13];
    const float* sr2_v   = (const float*)d_in[14];
    const float* local_w = (const float*)d_in[15];
    const float* local_b = (const float*)d_in[16];

    // workspace layout
    float* kv2 = (float*)d_ws;                                           // 32*128*225 f32
    unsigned short* kw = (unsigned short*)(kv2 + (size_t)B_ * C_ * NK_); // 64*240 rows x 256B (swizzled)
    float* bias_s = (float*)((char*)kw + (size_t)64 * 240 * 256);        // 64*240 f32
    unsigned short* vbuf = (unsigned short*)(bias_s + (size_t)64 * 240); // 64*64 rows x 512B (swizzled)

    srlocal_kernel<<<B_ * C_, 256, 0, stream>>>(
        x, sr1_w, sr1_g, sr1_b, sr1_m, sr1_v,
        sr2_w, sr2_g, sr2_b, sr2_m, sr2_v, local_w, local_b, kv2);
    kvw_kernel<<<dim3(B_, 2, 4), 256, 0, stream>>>(
        kv2, q_w, q_b, kv_w, kv_b, kw, bias_s, vbuf);
    attn_kernel<<<dim3(49, 2, B_), 256, 0, stream>>>(
        x, kw, bias_s, vbuf, (float*)d_out);
}

// Round 6
// 105.622 us; speedup vs baseline: 2.1953x; 1.3807x over previous
//
#include <hip/hip_runtime.h>
#include <hip/hip_bf16.h>

#define B_    32
#define C_    128
#define H_    56
#define W_    56
#define N_    3136
#define HK_   15
#define NK_   225
#define D_    64

typedef __attribute__((ext_vector_type(8))) short bf16x8;
typedef __attribute__((ext_vector_type(4))) float f32x4;

__device__ __forceinline__ float b2f(unsigned short u) {
    union { float f; unsigned int i; } x;
    x.i = ((unsigned int)u) << 16;
    return x.f;
}
__device__ __forceinline__ unsigned short f2b(float f) {
    __hip_bfloat16 h = __float2bfloat16(f);
    return *(unsigned short*)&h;
}

// async global -> LDS, 16B/lane; LDS dest wave-uniform base (HW adds lane*16)
__device__ __forceinline__ void gll16(const char* g, char* l) {
    __builtin_amdgcn_global_load_lds(
        (const __attribute__((address_space(1))) unsigned int*)g,
        (__attribute__((address_space(3))) unsigned int*)l,
        16, 0, 0);
}

// ---------------- Kernel 1: fused sr + local conv ----------------
__global__ __launch_bounds__(256) void srlocal_kernel(
        const float* __restrict__ x,
        const float* __restrict__ sr1_w, const float* __restrict__ sr1_g,
        const float* __restrict__ sr1_b, const float* __restrict__ sr1_m,
        const float* __restrict__ sr1_v, const float* __restrict__ sr2_w,
        const float* __restrict__ sr2_g, const float* __restrict__ sr2_b,
        const float* __restrict__ sr2_m, const float* __restrict__ sr2_v,
        const float* __restrict__ local_w, const float* __restrict__ local_b,
        float* __restrict__ kv2) {
    int bc = blockIdx.x;
    int c  = bc & (C_ - 1);
    int tid = threadIdx.x;
    __shared__ float xim[H_ * W_];
    __shared__ float kvt[HK_][HK_ + 1];

    const float* xp = x + (size_t)bc * (H_ * W_);
    for (int idx = tid; idx < (H_ * W_) / 4; idx += 256)
        ((float4*)xim)[idx] = ((const float4*)xp)[idx];
    __syncthreads();

    int p = tid;
    int oy = p / HK_, ox = p % HK_;
    if (p < NK_) {
        float s = 0.f;
#pragma unroll
        for (int ky = 0; ky < 4; ++ky) {
            int iy = oy * 4 - 2 + ky;
            if (iy < 0 || iy >= H_) continue;
#pragma unroll
            for (int kx = 0; kx < 4; ++kx) {
                int ix = ox * 4 - 2 + kx;
                if (ix < 0 || ix >= W_) continue;
                s += xim[iy * W_ + ix] * sr1_w[c * 16 + ky * 4 + kx];
            }
        }
        float inv1 = sr1_g[c] * rsqrtf(sr1_v[c] + 1e-5f);
        s = (s - sr1_m[c]) * inv1 + sr1_b[c];
        s = fmaxf(s, 0.f);
        s *= sr2_w[c];
        float inv2 = sr2_g[c] * rsqrtf(sr2_v[c] + 1e-5f);
        s = (s - sr2_m[c]) * inv2 + sr2_b[c];
        kvt[oy][ox] = s;
    }
    __syncthreads();
    if (p < NK_) {
        float v = kvt[oy][ox] + local_b[c];
#pragma unroll
        for (int dy = -1; dy <= 1; ++dy) {
            int yy = oy + dy;
            if (yy < 0 || yy >= HK_) continue;
#pragma unroll
            for (int dx = -1; dx <= 1; ++dx) {
                int xx = ox + dx;
                if (xx < 0 || xx >= HK_) continue;
                v += kvt[yy][xx] * local_w[c * 9 + (dy + 1) * 3 + (dx + 1)];
            }
        }
        kv2[(size_t)bc * NK_ + p] = v;
    }
}

// ---------------- Kernel 0: weight prep ----------------
// wkq_sw[h]: 128 rows(c) x 256B(c'), bf16, = 0.125*sum_e wq[e][c]*wk[e][c'], swizzled
// wv_sw[h]:  64 rows(e) x 256B(c'), bf16 cast of wv, swizzled
// kwb[h][c] = 0.125*sum_e kb[e]*wq[e][c];  wb[h][c'] = 0.125*sum_e qb[e]*wk[e][c']
// qkb[h] = 0.125*sum_e qb[e]*kb[e]
__global__ __launch_bounds__(256) void wprep_kernel(
        const float* __restrict__ q_w, const float* __restrict__ q_b,
        const float* __restrict__ kv_w, const float* __restrict__ kv_b,
        unsigned short* __restrict__ wkq_sw, unsigned short* __restrict__ wv_sw,
        float* __restrict__ kwb, float* __restrict__ wb, float* __restrict__ qkb) {
    int bx = blockIdx.x;          // 0..15
    int h  = bx >> 3, cg = bx & 7;
    int tid = threadIdx.x;
    __shared__ float wk_s[64][128];   // 32 KB
    __shared__ float wq_s[64][16];    // 4 KB

    for (int idx = tid; idx < 64 * 128; idx += 256)
        wk_s[idx >> 7][idx & 127] = kv_w[(size_t)(h * 64 + (idx >> 7)) * 128 + (idx & 127)];
    for (int idx = tid; idx < 64 * 16; idx += 256)
        wq_s[idx >> 4][idx & 15] = q_w[(size_t)(h * 64 + (idx >> 4)) * 128 + cg * 16 + (idx & 15)];
    __syncthreads();

    {
        int cl = tid >> 4;                // 0..15
        int c  = cg * 16 + cl;
        int cp0 = (tid & 15) * 8;
        float acc[8];
#pragma unroll
        for (int i = 0; i < 8; ++i) acc[i] = 0.f;
        for (int e = 0; e < 64; ++e) {
            float wqv = wq_s[e][cl];
#pragma unroll
            for (int i = 0; i < 8; ++i) acc[i] += wqv * wk_s[e][cp0 + i];
        }
        char* base = (char*)wkq_sw + (size_t)h * 32768 + (size_t)c * 256;
        ushort4 u0, u1;
        u0.x = f2b(acc[0] * 0.125f); u0.y = f2b(acc[1] * 0.125f);
        u0.z = f2b(acc[2] * 0.125f); u0.w = f2b(acc[3] * 0.125f);
        u1.x = f2b(acc[4] * 0.125f); u1.y = f2b(acc[5] * 0.125f);
        u1.z = f2b(acc[6] * 0.125f); u1.w = f2b(acc[7] * 0.125f);
        int sw = (c & 7) << 4;
        *(ushort4*)(base + ((cp0 * 2) ^ sw)) = u0;
        *(ushort4*)(base + ((cp0 * 2 + 8) ^ sw)) = u1;
    }
    // kwb for this cg's 16 c values
    if (tid < 16) {
        int cl = tid, c = cg * 16 + cl;
        float s = 0.f;
        for (int e = 0; e < 64; ++e) s += kv_b[h * 64 + e] * wq_s[e][cl];
        kwb[h * 128 + c] = s * 0.125f;
    }
    if (cg == 0) {
        if (tid < 128) {
            float s = 0.f;
            for (int e = 0; e < 64; ++e) s += q_b[h * 64 + e] * wk_s[e][tid];
            wb[h * 128 + tid] = s * 0.125f;
        }
        if (tid == 0) {
            float s = 0.f;
            for (int e = 0; e < 64; ++e) s += q_b[h * 64 + e] * kv_b[h * 64 + e];
            qkb[h] = s * 0.125f;
        }
    }
    if (cg == 1) {
        for (int idx = tid; idx < 64 * 128; idx += 256) {
            int e = idx >> 7, cp = idx & 127;
            unsigned short val = f2b(kv_w[(size_t)(128 + h * 64 + e) * 128 + cp]);
            *(unsigned short*)((char*)wv_sw + (size_t)h * 16384 + (size_t)e * 256 +
                               (((cp * 2) ^ ((e & 7) << 4)))) = val;
        }
    }
}

// ---------------- Kernel 2: kv projection via folded weights, MFMA ----------------
// kw:     [bh][256 rows m][256B c], bf16 swizzled (rows>=225: bias only, masked later)
// bias_s: [bh][256] f32, -1e30 for m>=225
// vbuf:   [bh][64 rows e][512B m], bf16 swizzled
#define L2B(r, cb) ((r) * 256 + ((cb) ^ (((r) & 7) << 4)))
__global__ __launch_bounds__(256, 2) void kvw_kernel(
        const float* __restrict__ kv2,
        const float* __restrict__ kv_b,
        const unsigned short* __restrict__ wkq_sw,
        const unsigned short* __restrict__ wv_sw,
        const float* __restrict__ kwb,
        const float* __restrict__ wb,
        const float* __restrict__ qkb,
        unsigned short* __restrict__ kw,
        float* __restrict__ bias_s,
        unsigned short* __restrict__ vbuf) {
    int b = blockIdx.x, h = blockIdx.y, mh = blockIdx.z;
    int bh = b * 2 + h;
    int m0 = mh * 64;
    int tid = threadIdx.x;
    int lo = tid & 15, hi = (tid >> 4) & 3, wid = tid >> 6;

    __shared__ char K2[16384];    // kv2T: 64 rows(m) x 256B(c')
    __shared__ char WQ[32768];    // wkq:  128 rows(c) x 256B(c')
    __shared__ char WV[16384];    // wv:   64 rows(e) x 256B(c')

    // stage WQ + WV via async DMA (pre-swizzled in global)
    {
        const char* srcQ = (const char*)wkq_sw + (size_t)h * 32768 + tid * 16;
        char* dstQ = WQ + wid * 1024;
#pragma unroll
        for (int i = 0; i < 8; ++i) gll16(srcQ + i * 4096, dstQ + i * 4096);
        const char* srcV = (const char*)wv_sw + (size_t)h * 16384 + tid * 16;
        char* dstV = WV + wid * 1024;
#pragma unroll
        for (int i = 0; i < 4; ++i) gll16(srcV + i * 4096, dstV + i * 4096);
    }
    // stage kv2T (reg transpose f32->bf16, swizzled)
    {
        int j = tid & 63;
        int mg = m0 + j;
        bool val = (mg < NK_);
#pragma unroll
        for (int it = 0; it < 8; ++it) {
            int c0 = (tid >> 6) * 4 + it * 16;
            ushort4 u;
            if (val) {
                const float* kp = kv2 + ((size_t)b * 128 + c0) * NK_ + mg;
                u.x = f2b(kp[0]);
                u.y = f2b(kp[NK_]);
                u.z = f2b(kp[2 * NK_]);
                u.w = f2b(kp[3 * NK_]);
            } else { u.x = 0; u.y = 0; u.z = 0; u.w = 0; }
            *(ushort4*)(K2 + L2B(j, c0 * 2)) = u;
        }
    }
    __syncthreads();

    // A-fragments: this wave's mtile (wid) rows
    bf16x8 aq[4];
#pragma unroll
    for (int ks = 0; ks < 4; ++ks)
        aq[ks] = *(const bf16x8*)(K2 + L2B(wid * 16 + lo, ks * 64 + hi * 16));

    // KW GEMM: D[m][c] = kv2T . WkqT  (+ kwb)
    char* kwB = (char*)kw + (size_t)bh * 65536;
#pragma unroll
    for (int ct = 0; ct < 8; ++ct) {
        f32x4 acc = {0.f, 0.f, 0.f, 0.f};
#pragma unroll
        for (int ks = 0; ks < 4; ++ks) {
            bf16x8 bq = *(const bf16x8*)(WQ + L2B(ct * 16 + lo, ks * 64 + hi * 16));
            acc = __builtin_amdgcn_mfma_f32_16x16x32_bf16(aq[ks], bq, acc, 0, 0, 0);
        }
        int c = ct * 16 + lo;
        float kb = kwb[h * 128 + c];
#pragma unroll
        for (int r = 0; r < 4; ++r) {
            int mg = m0 + wid * 16 + hi * 4 + r;
            *(unsigned short*)(kwB + (size_t)mg * 256 + (((c * 2) ^ ((mg & 7) << 4)))) =
                f2b(acc[r] + kb);
        }
    }

    // V GEMM: D[m][e] = kv2T . wv^T (+ vb); store transposed to vbuf[e][m]
    char* vB = (char*)vbuf + (size_t)bh * 32768;
#pragma unroll
    for (int et = 0; et < 4; ++et) {
        f32x4 acc = {0.f, 0.f, 0.f, 0.f};
#pragma unroll
        for (int ks = 0; ks < 4; ++ks) {
            bf16x8 bv = *(const bf16x8*)(WV + L2B(et * 16 + lo, ks * 64 + hi * 16));
            acc = __builtin_amdgcn_mfma_f32_16x16x32_bf16(aq[ks], bv, acc, 0, 0, 0);
        }
        int e = et * 16 + lo;
        float vb = kv_b[128 + h * 64 + e];
#pragma unroll
        for (int r = 0; r < 4; ++r) {
            int mg = m0 + wid * 16 + hi * 4 + r;
            *(unsigned short*)(vB + (size_t)e * 512 + (((mg * 2) ^ ((e & 7) << 4)))) =
                f2b(acc[r] + vb);
        }
    }

    // bias_s: dot(kv2T[m], wb) + qkb
    if (tid < 64) {
        int mg = m0 + tid;
        float s;
        if (mg >= NK_) s = -1e30f;
        else {
            s = qkb[h];
            for (int i = 0; i < 128; ++i) {
                int cp = (i + (tid & 7) * 16) & 127;
                s += b2f(*(const unsigned short*)(K2 + L2B(tid, cp * 2))) * wb[h * 128 + cp];
            }
        }
        bias_s[(size_t)bh * 256 + mg] = s;
    }
}

// ---------------- Kernel 3: fused attention, LDS-fed MFMA ----------------
#define XTB(j, c) ((j) * 256 + (((c) * 2) ^ (((j) & 7) << 4)))
#define PSB(j, m) ((j) * 512 + (((m) * 2) ^ (((j) & 7) << 4)))
#define KWB(rl, cb) ((rl) * 256 + ((cb) ^ (((rl) & 7) << 4)))
#define CVB(e, cb)  ((e) * 512 + ((cb) ^ (((e) & 7) << 4)))

__global__ __launch_bounds__(256, 2) void attn_kernel(
        const float* __restrict__ x,
        const unsigned short* __restrict__ kw,
        const float* __restrict__ bias_s,
        const unsigned short* __restrict__ vbuf,
        float* __restrict__ out) {
    int jt = blockIdx.x;        // 0..48
    int h  = blockIdx.y;        // 0..1
    int bb = blockIdx.z;        // 0..31
    int n0 = jt * 64;
    int bh = bb * 2 + h;
    int tid = threadIdx.x;
    int lo  = tid & 15;
    int hi  = (tid >> 4) & 3;
    int wid = tid >> 6;
    int jw  = wid * 16;

    __shared__ char A[32768];    // xt (16KB) then ps (32KB)
    __shared__ char Bt[12288];   // kw tile: 48 rows x 256B
    __shared__ char Cv[32768];   // v: 64 rows x 512B

    const char* kwG = (const char*)kw + (size_t)bh * 65536;
    const char* vG  = (const char*)vbuf + (size_t)bh * 32768;

    float bs[15];
    const float* bsp = bias_s + (size_t)bh * 256;
#pragma unroll
    for (int mt = 0; mt < 15; ++mt) bs[mt] = bsp[mt * 16 + lo];

    {
        char* dstB = Bt + wid * 1024;
        const char* srcB = kwG + tid * 16;
#pragma unroll
        for (int i = 0; i < 3; ++i) gll16(srcB + i * 4096, dstB + i * 4096);
        char* dstC = Cv + wid * 1024;
        const char* srcC = vG + tid * 16;
#pragma unroll
        for (int i = 0; i < 8; ++i) gll16(srcC + i * 4096, dstC + i * 4096);
    }

#pragma unroll
    for (int it = 0; it < 8; ++it) {
        int j  = tid & 63;
        int c0 = (tid >> 6) * 4 + it * 16;
        const float* xp = x + ((size_t)bb * 128 + c0) * N_ + n0 + j;
        ushort4 u;
        u.x = f2b(xp[0]);
        u.y = f2b(xp[(size_t)N_]);
        u.z = f2b(xp[2 * (size_t)N_]);
        u.w = f2b(xp[3 * (size_t)N_]);
        *(ushort4*)(A + XTB(j, c0)) = u;
    }
    __syncthreads();

    bf16x8 aq[4];
#pragma unroll
    for (int ks = 0; ks < 4; ++ks)
        aq[ks] = *(const bf16x8*)(A + XTB(jw + lo, ks * 32 + hi * 8));

    f32x4 s[15];
#pragma unroll
    for (int t = 0; t < 5; ++t) {
#pragma unroll
        for (int ml = 0; ml < 3; ++ml) {
            f32x4 acc = {0.f, 0.f, 0.f, 0.f};
#pragma unroll
            for (int ks = 0; ks < 4; ++ks) {
                bf16x8 bk = *(const bf16x8*)(Bt + KWB(ml * 16 + lo, ks * 64 + hi * 16));
                acc = __builtin_amdgcn_mfma_f32_16x16x32_bf16(aq[ks], bk, acc, 0, 0, 0);
            }
            s[t * 3 + ml] = acc;
        }
        if (t < 4) {
            __syncthreads();
            const char* srcB = kwG + (t + 1) * 12288 + tid * 16;
            char* dstB = Bt + wid * 1024;
#pragma unroll
            for (int i = 0; i < 3; ++i) gll16(srcB + i * 4096, dstB + i * 4096);
            __syncthreads();
        }
    }

#pragma unroll
    for (int mt = 0; mt < 15; ++mt) {
#pragma unroll
        for (int r = 0; r < 4; ++r) s[mt][r] += bs[mt];
    }

    float mx[4];
#pragma unroll
    for (int r = 0; r < 4; ++r) {
        float m0v = s[0][r];
#pragma unroll
        for (int mt = 1; mt < 15; ++mt) m0v = fmaxf(m0v, s[mt][r]);
        mx[r] = m0v;
    }
#pragma unroll
    for (int d = 1; d < 16; d <<= 1) {
#pragma unroll
        for (int r = 0; r < 4; ++r) mx[r] = fmaxf(mx[r], __shfl_xor(mx[r], d));
    }
    float sm[4] = {0.f, 0.f, 0.f, 0.f};
#pragma unroll
    for (int mt = 0; mt < 15; ++mt) {
#pragma unroll
        for (int r = 0; r < 4; ++r) {
            float pe = __expf(s[mt][r] - mx[r]);
            s[mt][r] = pe;
            sm[r] += pe;
        }
    }
#pragma unroll
    for (int d = 1; d < 16; d <<= 1) {
#pragma unroll
        for (int r = 0; r < 4; ++r) sm[r] += __shfl_xor(sm[r], d);
    }
    float rinv[4];
#pragma unroll
    for (int r = 0; r < 4; ++r) rinv[r] = 1.f / sm[r];

#pragma unroll
    for (int mt = 0; mt < 15; ++mt) {
#pragma unroll
        for (int r = 0; r < 4; ++r)
            *(unsigned short*)(A + PSB(jw + hi * 4 + r, mt * 16 + lo)) =
                f2b(s[mt][r] * rinv[r]);
    }
#pragma unroll
    for (int r = 0; r < 4; ++r)
        *(unsigned short*)(A + PSB(jw + hi * 4 + r, 240 + lo)) = 0;

    bf16x8 bp[8];
#pragma unroll
    for (int ks = 0; ks < 8; ++ks)
        bp[ks] = *(const bf16x8*)(A + PSB(jw + lo, ks * 32 + hi * 8));
#pragma unroll
    for (int et = 0; et < 4; ++et) {
        f32x4 acc = {0.f, 0.f, 0.f, 0.f};
#pragma unroll
        for (int ks = 0; ks < 8; ++ks) {
            bf16x8 av = *(const bf16x8*)(Cv + CVB(et * 16 + lo, ks * 64 + hi * 16));
            acc = __builtin_amdgcn_mfma_f32_16x16x32_bf16(av, bp[ks], acc, 0, 0, 0);
        }
        int e = et * 16 + hi * 4;
#pragma unroll
        for (int r = 0; r < 4; ++r)
            out[((size_t)bb * 128 + h * 64 + e + r) * N_ + n0 + jw + lo] = acc[r];
    }
}

extern "C" void kernel_launch(void* const* d_in, const int* in_sizes, int n_in,
                              void* d_out, int out_size, void* d_ws, size_t ws_size,
                              hipStream_t stream) {
    const float* x       = (const float*)d_in[0];
    const float* q_w     = (const float*)d_in[1];
    const float* q_b     = (const float*)d_in[2];
    const float* kv_w    = (const float*)d_in[3];
    const float* kv_b    = (const float*)d_in[4];
    const float* sr1_w   = (const float*)d_in[5];
    const float* sr1_g   = (const float*)d_in[6];
    const float* sr1_b   = (const float*)d_in[7];
    const float* sr1_m   = (const float*)d_in[8];
    const float* sr1_v   = (const float*)d_in[9];
    const float* sr2_w   = (const float*)d_in[10];
    const float* sr2_g   = (const float*)d_in[11];
    const float* sr2_b   = (const float*)d_in[12];
    const float* sr2_m   = (const float*)d_in[13];
    const float* sr2_v   = (const float*)d_in[14];
    const float* local_w = (const float*)d_in[15];
    const float* local_b = (const float*)d_in[16];

    // workspace layout (bytes, 256-aligned sections)
    char* ws = (char*)d_ws;
    float* kv2              = (float*)(ws + 0);                 // 3,686,400 B
    unsigned short* wkq_sw  = (unsigned short*)(ws + 3686400);  //    65,536 B
    unsigned short* wv_sw   = (unsigned short*)(ws + 3751936);  //    32,768 B
    unsigned short* kw      = (unsigned short*)(ws + 3784704);  // 4,194,304 B
    unsigned short* vbuf    = (unsigned short*)(ws + 7979008);  // 2,097,152 B
    float* bias_s           = (float*)(ws + 10076160);          //    65,536 B
    float* kwb              = (float*)(ws + 10141696);          //     1,024 B
    float* wb               = (float*)(ws + 10142720);          //     1,024 B
    float* qkb              = (float*)(ws + 10143744);          //         8 B

    wprep_kernel<<<16, 256, 0, stream>>>(q_w, q_b, kv_w, kv_b,
                                         wkq_sw, wv_sw, kwb, wb, qkb);
    srlocal_kernel<<<B_ * C_, 256, 0, stream>>>(
        x, sr1_w, sr1_g, sr1_b, sr1_m, sr1_v,
        sr2_w, sr2_g, sr2_b, sr2_m, sr2_v, local_w, local_b, kv2);
    kvw_kernel<<<dim3(B_, 2, 4), 256, 0, stream>>>(
        kv2, kv_b, wkq_sw, wv_sw, kwb, wb, qkb, kw, bias_s, vbuf);
    attn_kernel<<<dim3(49, 2, B_), 256, 0, stream>>>(
        x, kw, bias_s, vbuf, (float*)d_out);
}